// Round 2
// baseline (346.616 us; speedup 1.0000x reference)
//
#include <hip/hip_runtime.h>

#define NEG_SLOPE 0.2f
#define SCAN_B 1024

typedef __attribute__((ext_vector_type(8))) short bf16x8;   // MFMA A/B frag
typedef __attribute__((ext_vector_type(4))) float f32x4;    // MFMA C/D frag

// fp32 -> bf16 round-to-nearest-even (no NaN inputs here).
__device__ __forceinline__ unsigned short f2b(float f) {
    unsigned int u = __float_as_uint(f);
    u += 0x7FFFu + ((u >> 16) & 1u);
    return (unsigned short)(u >> 16);
}
__device__ __forceinline__ float blo(unsigned int u) { return __uint_as_float(u << 16); }
__device__ __forceinline__ float bhi(unsigned int u) { return __uint_as_float(u & 0xFFFF0000u); }

// Fused: blocks [0,RB) = CSR rank histogram; blocks [RB,..) = layer-1 scores.
__global__ __launch_bounds__(256) void k_ratt(
    const int* __restrict__ ei, int E, int EN,
    int* __restrict__ cnt, unsigned short* __restrict__ rank,
    const float* __restrict__ x, const float* __restrict__ W1,
    const float* __restrict__ as1, const float* __restrict__ ad1,
    float* __restrict__ asrc, float* __restrict__ adst, int N, int RB)
{
    if (blockIdx.x < RB) {
        int e = blockIdx.x * 256 + threadIdx.x;
        if (e >= EN) return;
        int dst = (e < E) ? ei[E + e] : (e - E);
        unsigned short r = (unsigned short)atomicAdd(&cnt[dst], 1);
        __builtin_nontemporal_store(r, rank + e);
        return;
    }
    __shared__ float s_wa[32], s_wd[32];
    int t = threadIdx.x;
    if (t < 32) {
        int k = t >> 2, hh = t & 3;
        float sa = 0.f, sd = 0.f;
        for (int cc = 0; cc < 32; cc++) {
            float w = W1[k * 128 + hh * 32 + cc];
            sa = fmaf(w, as1[hh * 32 + cc], sa);
            sd = fmaf(w, ad1[hh * 32 + cc], sd);
        }
        s_wa[t] = sa;   // index k*4+hh == t
        s_wd[t] = sd;
    }
    __syncthreads();
    int g = (blockIdx.x - RB) * 256 + t;
    int n = g >> 2;
    if (n >= N) return;
    int h = g & 3;
    const float* xr = x + (size_t)n * 8;
    float sa = 0.f, sd = 0.f;
    #pragma unroll
    for (int k = 0; k < 8; k++) {
        float xv = xr[k];
        sa = fmaf(xv, s_wa[k * 4 + h], sa);
        sd = fmaf(xv, s_wd[k * 4 + h], sd);
    }
    asrc[n * 4 + h] = sa;
    adst[n * 4 + h] = sd;
}

// Scan phase A: per-1024-tile sums.
__global__ __launch_bounds__(SCAN_B) void k_scanA(
    const int* __restrict__ cnt, int* __restrict__ bsum, int N)
{
    __shared__ int red[SCAN_B];
    int t = threadIdx.x;
    int i = blockIdx.x * SCAN_B + t;
    red[t] = (i < N) ? cnt[i] : 0;
    __syncthreads();
    #pragma unroll
    for (int off = SCAN_B / 2; off > 0; off >>= 1) {
        if (t < off) red[t] += red[t + off];
        __syncthreads();
    }
    if (t == 0) bsum[blockIdx.x] = red[0];
}

// Scan phase C with inlined phase B: each block reduces bsum[0..b) itself
// (G <= 1024), then intra-tile exclusive scan -> rowptr[N+1].
__global__ __launch_bounds__(SCAN_B) void k_scanC(
    const int* __restrict__ cnt, const int* __restrict__ bsum,
    int* __restrict__ rowptr, int N, int G)
{
    __shared__ int s[SCAN_B];
    int t = threadIdx.x, b = blockIdx.x;
    s[t] = (t < b && t < G) ? bsum[t] : 0;
    __syncthreads();
    #pragma unroll
    for (int off = SCAN_B / 2; off > 0; off >>= 1) {
        if (t < off) s[t] += s[t + off];
        __syncthreads();
    }
    int boff = s[0];
    __syncthreads();
    int i = b * SCAN_B + t;
    int v = (i < N) ? cnt[i] : 0;
    s[t] = v;
    __syncthreads();
    for (int off = 1; off < SCAN_B; off <<= 1) {
        int u = (t >= off) ? s[t - off] : 0;
        __syncthreads();
        s[t] += u;
        __syncthreads();
    }
    int excl = s[t] - v + boff;
    if (i < N) {
        rowptr[i] = excl;
        if (i == N - 1) rowptr[N] = excl + v;
    }
}

// Fused: blocks [0,PB) = atomic-free CSR placement; blocks [PB,PB+8) = pack W2.
__global__ __launch_bounds__(256) void k_plpk(
    const int* __restrict__ ei, int E, int EN,
    const int* __restrict__ rowptr, const unsigned short* __restrict__ rank,
    int* __restrict__ esrc,
    const float* __restrict__ W2, unsigned short* __restrict__ W2p, int PB)
{
    if (blockIdx.x < PB) {
        int e = blockIdx.x * 256 + threadIdx.x;
        if (e >= EN) return;
        int src, dst;
        if (e < E) { src = ei[e]; dst = ei[E + e]; }
        else       { src = dst = e - E; }
        esrc[rowptr[dst] + (int)rank[e]] = src;
        return;
    }
    int w = threadIdx.x >> 6, lane = threadIdx.x & 63;
    int quad = lane >> 4, lanelo = lane & 15;
    int tile_n = blockIdx.x - PB;               // 0..7
    size_t base = (((size_t)tile_n * 4 + w) * 64 + lane) * 8;
    #pragma unroll
    for (int j = 0; j < 8; j++) {
        int k = w * 32 + quad * 8 + j;
        int n = tile_n * 16 + lanelo;
        W2p[base + j] = f2b(W2[k * 128 + n]);
    }
}

// Layer-1 aggregation in INPUT space, 8-wide edge batch.
// 8 lanes/node: lane = head*2 + dim-half.
__global__ __launch_bounds__(256) void k_aggx(
    const int* __restrict__ rowptr, const int* __restrict__ esrc,
    const float* __restrict__ x, const float* __restrict__ asrc,
    const float* __restrict__ adst,
    float* __restrict__ y, float* __restrict__ denom, int N)
{
    int gid = blockIdx.x * 256 + threadIdx.x;
    int node = gid >> 3;
    if (node >= N) return;
    int l8 = threadIdx.x & 7;
    int h = l8 >> 1;
    int dh = (l8 & 1) << 2;
    float ad = adst[node * 4 + h];
    float a0 = 0.f, a1 = 0.f, a2 = 0.f, a3 = 0.f, d = 0.f;
    int j = rowptr[node], end = rowptr[node + 1];
    for (; j + 8 <= end; j += 8) {
        int s[8];
        #pragma unroll
        for (int i = 0; i < 8; i++) s[i] = esrc[j + i];
        float A[8];
        #pragma unroll
        for (int i = 0; i < 8; i++) A[i] = asrc[s[i] * 4 + h];
        float4 xv[8];
        #pragma unroll
        for (int i = 0; i < 8; i++)
            xv[i] = *reinterpret_cast<const float4*>(x + (size_t)s[i] * 8 + dh);
        #pragma unroll
        for (int i = 0; i < 8; i++) {
            float a = A[i] + ad;
            a = a > 0.f ? a : NEG_SLOPE * a;
            float w = __expf(a);
            a0 = fmaf(w, xv[i].x, a0); a1 = fmaf(w, xv[i].y, a1);
            a2 = fmaf(w, xv[i].z, a2); a3 = fmaf(w, xv[i].w, a3); d += w;
        }
    }
    if (j + 4 <= end) {
        int s[4];
        #pragma unroll
        for (int i = 0; i < 4; i++) s[i] = esrc[j + i];
        float A[4];
        #pragma unroll
        for (int i = 0; i < 4; i++) A[i] = asrc[s[i] * 4 + h];
        float4 xv[4];
        #pragma unroll
        for (int i = 0; i < 4; i++)
            xv[i] = *reinterpret_cast<const float4*>(x + (size_t)s[i] * 8 + dh);
        #pragma unroll
        for (int i = 0; i < 4; i++) {
            float a = A[i] + ad;
            a = a > 0.f ? a : NEG_SLOPE * a;
            float w = __expf(a);
            a0 = fmaf(w, xv[i].x, a0); a1 = fmaf(w, xv[i].y, a1);
            a2 = fmaf(w, xv[i].z, a2); a3 = fmaf(w, xv[i].w, a3); d += w;
        }
        j += 4;
    }
    for (; j < end; j++) {
        int src = esrc[j];
        float a = asrc[src * 4 + h] + ad;
        a = a > 0.f ? a : NEG_SLOPE * a;
        float w = __expf(a);
        float4 xv = *reinterpret_cast<const float4*>(x + (size_t)src * 8 + dh);
        a0 = fmaf(w, xv.x, a0); a1 = fmaf(w, xv.y, a1);
        a2 = fmaf(w, xv.z, a2); a3 = fmaf(w, xv.w, a3); d += w;
    }
    float4 o = {a0, a1, a2, a3};
    *reinterpret_cast<float4*>(y + ((size_t)node * 4 + h) * 8 + dh) = o;
    if (dh == 0) denom[node * 4 + h] = d;
}

// Layer-2 feature transform with fused out1 computation.
// h2 is written SPLIT by head-pair: hA = heads 0,1 (64ch rows), hB = heads 2,3.
__global__ __launch_bounds__(256) void k_feat2(
    const float* __restrict__ y, const float* __restrict__ denom,
    const float* __restrict__ W1, const float* __restrict__ bias1,
    const unsigned short* __restrict__ W2p,
    const float* __restrict__ att_src, const float* __restrict__ att_dst,
    unsigned short* __restrict__ hA, unsigned short* __restrict__ hB,
    float* __restrict__ asrc, float* __restrict__ adst, int N)
{
    __shared__ uint4 s_tile[512];               // 32 nodes x 256B
    char* s_a = reinterpret_cast<char*>(s_tile);
    int t = threadIdx.x;
    int mbase = blockIdx.x * 32;

    // ---- stage 1: out1 tile into LDS (XOR-swizzled) ----
    {
        int nl = t >> 3;                        // 0..31
        int seg = t & 7;                        // 16 channels each
        int node = mbase + nl;
        if (node >= N) node = N - 1;            // clamp; stores guarded later
        int head = seg >> 1;
        const float* yr = y + ((size_t)node * 4 + head) * 8;
        float inv = 1.f / denom[node * 4 + head];
        float y8[8];
        #pragma unroll
        for (int k = 0; k < 8; k++) y8[k] = yr[k];
        int c0 = seg * 16;
        float acc16[16];
        #pragma unroll
        for (int c = 0; c < 16; c++) acc16[c] = 0.f;
        #pragma unroll
        for (int k = 0; k < 8; k++) {
            float yk = y8[k];
            const float4* wr = reinterpret_cast<const float4*>(W1 + k * 128 + c0);
            #pragma unroll
            for (int q = 0; q < 4; q++) {
                float4 wv = wr[q];
                acc16[q * 4 + 0] = fmaf(yk, wv.x, acc16[q * 4 + 0]);
                acc16[q * 4 + 1] = fmaf(yk, wv.y, acc16[q * 4 + 1]);
                acc16[q * 4 + 2] = fmaf(yk, wv.z, acc16[q * 4 + 2]);
                acc16[q * 4 + 3] = fmaf(yk, wv.w, acc16[q * 4 + 3]);
            }
        }
        unsigned int dw[8];
        #pragma unroll
        for (int c = 0; c < 8; c++) {
            float v0 = acc16[2 * c]     * inv + bias1[c0 + 2 * c];
            float v1 = acc16[2 * c + 1] * inv + bias1[c0 + 2 * c + 1];
            v0 = v0 > 0.f ? v0 : 0.f;
            v1 = v1 > 0.f ? v1 : 0.f;
            dw[c] = ((unsigned int)f2b(v1) << 16) | f2b(v0);
        }
        int byte0 = nl * 256 + seg * 32;
        int swz = (nl & 7) << 4;
        *reinterpret_cast<uint4*>(&s_a[byte0 ^ swz]) =
            make_uint4(dw[0], dw[1], dw[2], dw[3]);
        *reinterpret_cast<uint4*>(&s_a[(byte0 + 16) ^ swz]) =
            make_uint4(dw[4], dw[5], dw[6], dw[7]);
    }
    __syncthreads();

    // ---- stage 2: MFMA, A from LDS ----
    int w = t >> 6;
    int lane = t & 63;
    int quad = lane >> 4, lanelo = lane & 15;
    int wcb = w * 32;                           // wave col base == head w * 32

    f32x4 acc[2][2];
    #pragma unroll
    for (int rt = 0; rt < 2; rt++)
        #pragma unroll
        for (int ct = 0; ct < 2; ct++)
            acc[rt][ct] = (f32x4){0.f, 0.f, 0.f, 0.f};

    #pragma unroll
    for (int kc = 0; kc < 4; kc++) {
        bf16x8 a[2], b[2];
        #pragma unroll
        for (int rt = 0; rt < 2; rt++) {
            int nl = rt * 16 + lanelo;
            int byte = nl * 256 + kc * 64 + quad * 16;
            a[rt] = *reinterpret_cast<const bf16x8*>(&s_a[byte ^ ((nl & 7) << 4)]);
        }
        #pragma unroll
        for (int ct = 0; ct < 2; ct++) {
            int tile_n = w * 2 + ct;
            b[ct] = *reinterpret_cast<const bf16x8*>(
                W2p + (((size_t)tile_n * 4 + kc) * 64 + lane) * 8);
        }
        #pragma unroll
        for (int rt = 0; rt < 2; rt++)
            #pragma unroll
            for (int ct = 0; ct < 2; ct++)
                acc[rt][ct] = __builtin_amdgcn_mfma_f32_16x16x32_bf16(
                    a[rt], b[ct], acc[rt][ct], 0, 0, 0);
    }

    // Epilogue. C/D layout: n = lane&15, m = quad*4 + reg.
    unsigned short* T = (w < 2) ? hA : hB;
    int lcb = (w & 1) * 32;                     // head-pair-local col base
    float as_[2], ad_[2];
    #pragma unroll
    for (int ct = 0; ct < 2; ct++) {
        int col = wcb + ct * 16 + lanelo;
        as_[ct] = att_src[col];
        ad_[ct] = att_dst[col];
    }
    #pragma unroll
    for (int rt = 0; rt < 2; rt++) {
        #pragma unroll
        for (int reg = 0; reg < 4; reg++) {
            int node = mbase + rt * 16 + quad * 4 + reg;
            bool ok = node < N;
            float v0 = acc[rt][0][reg], v1 = acc[rt][1][reg];
            if (ok) {
                T[(size_t)node * 64 + lcb + lanelo]      = f2b(v0);
                T[(size_t)node * 64 + lcb + 16 + lanelo] = f2b(v1);
            }
            float ps = v0 * as_[0] + v1 * as_[1];
            float pd = v0 * ad_[0] + v1 * ad_[1];
            #pragma unroll
            for (int off = 8; off >= 1; off >>= 1) {
                ps += __shfl_xor(ps, off, 64);
                pd += __shfl_xor(pd, off, 64);
            }
            if (ok && lanelo == 0) {
                asrc[node * 4 + w] = ps;
                adst[node * 4 + w] = pd;
            }
        }
    }
}

// Layer-2 aggregation, head-pair split. Blocks [0,NB) do heads {0,1} from hA,
// blocks [NB,2NB) do heads {2,3} from hB. Per phase the gather table is only
// 12.8 MB (128 B rows) -> higher L2 hit rate; 128 B (2 lines) per edge.
// 16 lanes/node, 4 ch/lane; writes alpha-normalized per-head-pair partials.
__global__ __launch_bounds__(256) void k_agg2h(
    const int* __restrict__ rowptr, const int* __restrict__ esrc,
    const unsigned short* __restrict__ hA, const unsigned short* __restrict__ hB,
    const float* __restrict__ asrc, const float* __restrict__ adst,
    float* __restrict__ pA, float* __restrict__ pB, int N, int NB)
{
    int phase = (blockIdx.x >= NB) ? 1 : 0;
    const uint2* hp = reinterpret_cast<const uint2*>(phase ? hB : hA);
    float* pp = phase ? pB : pA;
    int gid = (blockIdx.x - phase * NB) * 256 + threadIdx.x;
    int node = gid >> 4;
    if (node >= N) return;
    int l4 = threadIdx.x & 15;
    int head = phase * 2 + (l4 >> 3);
    float ad = adst[node * 4 + head];
    float a0 = 0.f, a1 = 0.f, a2 = 0.f, a3 = 0.f, d = 0.f;
    int j = rowptr[node], end = rowptr[node + 1];

    for (; j + 8 <= end; j += 8) {
        int s[8];
        #pragma unroll
        for (int i = 0; i < 8; i++) s[i] = esrc[j + i];
        float A[8];
        #pragma unroll
        for (int i = 0; i < 8; i++) A[i] = asrc[s[i] * 4 + head];
        uint2 u[8];
        #pragma unroll
        for (int i = 0; i < 8; i++) u[i] = hp[(size_t)s[i] * 16 + l4];
        #pragma unroll
        for (int i = 0; i < 8; i++) {
            float a = A[i] + ad;
            a = a > 0.f ? a : NEG_SLOPE * a;
            float w = __expf(a);
            a0 = fmaf(w, blo(u[i].x), a0); a1 = fmaf(w, bhi(u[i].x), a1);
            a2 = fmaf(w, blo(u[i].y), a2); a3 = fmaf(w, bhi(u[i].y), a3);
            d += w;
        }
    }
    if (j + 4 <= end) {
        int s[4];
        #pragma unroll
        for (int i = 0; i < 4; i++) s[i] = esrc[j + i];
        float A[4];
        #pragma unroll
        for (int i = 0; i < 4; i++) A[i] = asrc[s[i] * 4 + head];
        uint2 u[4];
        #pragma unroll
        for (int i = 0; i < 4; i++) u[i] = hp[(size_t)s[i] * 16 + l4];
        #pragma unroll
        for (int i = 0; i < 4; i++) {
            float a = A[i] + ad;
            a = a > 0.f ? a : NEG_SLOPE * a;
            float w = __expf(a);
            a0 = fmaf(w, blo(u[i].x), a0); a1 = fmaf(w, bhi(u[i].x), a1);
            a2 = fmaf(w, blo(u[i].y), a2); a3 = fmaf(w, bhi(u[i].y), a3);
            d += w;
        }
        j += 4;
    }
    for (; j < end; j++) {
        int src = esrc[j];
        float a = asrc[src * 4 + head] + ad;
        a = a > 0.f ? a : NEG_SLOPE * a;
        float w = __expf(a);
        uint2 u = hp[(size_t)src * 16 + l4];
        a0 = fmaf(w, blo(u.x), a0); a1 = fmaf(w, bhi(u.x), a1);
        a2 = fmaf(w, blo(u.y), a2); a3 = fmaf(w, bhi(u.y), a3);
        d += w;
    }

    float inv = 1.f / d;
    float v0 = a0 * inv, v1 = a1 * inv, v2 = a2 * inv, v3 = a3 * inv;
    // sum the two heads of this pair: lane bit 3 of l4 selects the head
    v0 += __shfl_xor(v0, 8, 64);
    v1 += __shfl_xor(v1, 8, 64);
    v2 += __shfl_xor(v2, 8, 64);
    v3 += __shfl_xor(v3, 8, 64);
    if (l4 < 8) {
        float4 o = {v0, v1, v2, v3};
        *reinterpret_cast<float4*>(pp + (size_t)node * 32 + l4 * 4) = o;
    }
}

// Final combine: out = relu(0.25*(pA+pB) + bias2) . Wlin + blin. 8 lanes/node.
__global__ __launch_bounds__(256) void k_fin(
    const float* __restrict__ pA, const float* __restrict__ pB,
    const float* __restrict__ bias2, const float* __restrict__ Wlin,
    const float* __restrict__ blin, float* __restrict__ out, int N)
{
    int gid = blockIdx.x * 256 + threadIdx.x;
    int node = gid >> 3;
    if (node >= N) return;
    int l8 = threadIdx.x & 7;
    float4 a = *reinterpret_cast<const float4*>(pA + (size_t)node * 32 + l8 * 4);
    float4 b = *reinterpret_cast<const float4*>(pB + (size_t)node * 32 + l8 * 4);
    float4 bs = *reinterpret_cast<const float4*>(bias2 + l8 * 4);
    float4 wl = *reinterpret_cast<const float4*>(Wlin + l8 * 4);
    float t = 0.f;
    float m;
    m = 0.25f * (a.x + b.x) + bs.x; m = m > 0.f ? m : 0.f; t = fmaf(m, wl.x, t);
    m = 0.25f * (a.y + b.y) + bs.y; m = m > 0.f ? m : 0.f; t = fmaf(m, wl.y, t);
    m = 0.25f * (a.z + b.z) + bs.z; m = m > 0.f ? m : 0.f; t = fmaf(m, wl.z, t);
    m = 0.25f * (a.w + b.w) + bs.w; m = m > 0.f ? m : 0.f; t = fmaf(m, wl.w, t);
    t += __shfl_xor(t, 1, 64);
    t += __shfl_xor(t, 2, 64);
    t += __shfl_xor(t, 4, 64);
    if (l8 == 0) out[node] = t + blin[0];
}

extern "C" void kernel_launch(void* const* d_in, const int* in_sizes, int n_in,
                              void* d_out, int out_size, void* d_ws, size_t ws_size,
                              hipStream_t stream)
{
    const float* x   = (const float*)d_in[0];
    const int*   ei  = (const int*)  d_in[1];
    const float* W1  = (const float*)d_in[2];
    const float* as1 = (const float*)d_in[3];
    const float* ad1 = (const float*)d_in[4];
    const float* b1  = (const float*)d_in[5];
    const float* W2  = (const float*)d_in[6];
    const float* as2 = (const float*)d_in[7];
    const float* ad2 = (const float*)d_in[8];
    const float* b2  = (const float*)d_in[9];
    const float* Wl  = (const float*)d_in[10];
    const float* bl  = (const float*)d_in[11];
    float* out = (float*)d_out;

    int N  = in_sizes[0] / 8;
    int E  = in_sizes[1] / 2;
    int EN = E + N;
    int G  = (N + SCAN_B - 1) / SCAN_B;

    float* ws    = (float*)d_ws;
    unsigned short* hA = (unsigned short*)ws;   // N*64 bf16 (heads 0,1)
    unsigned short* hB = hA + (size_t)N * 64;   // N*64 bf16 (heads 2,3)
    float* B     = ws + (size_t)N * 64;         // region: rank, then y, then pA/pB
    float* y     = B;                           // N*32 fp32 (layer-1 aggregate)
    unsigned short* rank = (unsigned short*)B;  // EN u16, dead before k_aggx
    float* pA    = B;                           // N*32 fp32 (y dead by k_agg2h)
    float* pB    = B + (size_t)N * 32;          // N*32 fp32
    float* asrc  = B + (size_t)N * 128;         // N*4
    float* adst  = asrc + (size_t)N * 4;        // N*4
    int* cnt     = (int*)(adst + (size_t)N * 4);// N
    int* rowptr  = cnt + N;                     // N+1
    int* bsum    = rowptr + N + 1;              // G
    int* esrc    = bsum + G;                    // EN
    unsigned short* W2p = (unsigned short*)(esrc + EN);  // 16384 bf16
    float* denom = (float*)(W2p + 16384);       // N*4

    int eb = (EN + 255) / 256;
    int ab = (N + 63) / 64;                     // att1 blocks (4 lanes/node)
    int nb = (N + 15) / 16;                     // agg2: 16 nodes/block

    hipMemsetAsync(cnt, 0, (size_t)N * sizeof(int), stream);
    k_ratt<<<eb + ab, 256, 0, stream>>>(ei, E, EN, cnt, rank,
                                        x, W1, as1, ad1, asrc, adst, N, eb);
    k_scanA<<<G, SCAN_B, 0, stream>>>(cnt, bsum, N);
    k_scanC<<<G, SCAN_B, 0, stream>>>(cnt, bsum, rowptr, N, G);
    k_plpk<<<eb + 8, 256, 0, stream>>>(ei, E, EN, rowptr, rank, esrc, W2, W2p, eb);

    // Layer 1 (input-space aggregation: no h1 materialization)
    k_aggx<<<(N + 31) / 32, 256, 0, stream>>>(rowptr, esrc, x, asrc, adst,
                                              y, denom, N);

    // Layer 2: fused out1 + matmul + scores; then head-pair-split aggregation
    k_feat2<<<(N + 31) / 32, 256, 0, stream>>>(y, denom, W1, b1, W2p,
                                               as2, ad2, hA, hB, asrc, adst, N);
    k_agg2h<<<2 * nb, 256, 0, stream>>>(rowptr, esrc, hA, hB, asrc, adst,
                                        pA, pB, N, nb);
    k_fin<<<(N * 8 + 255) / 256, 256, 0, stream>>>(pA, pB, b2, Wl, bl, out, N);
}